// Round 6
// baseline (297.520 us; speedup 1.0000x reference)
//
#include <hip/hip_runtime.h>
#include <math.h>

#define TH     32              // output rows per block strip
#define NSTEP  (TH + 10)       // input rows iterated (vertical halo 5+5)
#define WIDTH  226             // output float-columns per block
#define LPLANE 288             // padded LDS plane (reads reach idx 273)

__global__ void zero_kernel(float* ws) { ws[0] = 0.0f; }

__global__ void finalize_kernel(const float* ws, float* out, float inv_n) {
    out[0] = 1.0f - ws[0] * inv_n;
}

__global__ void reduce_kernel(const float* __restrict__ ws, float* __restrict__ out,
                              int n, float inv_n) {
    __shared__ float s[16];
    float a = 0.0f;
    for (int i = threadIdx.x; i < n; i += 1024) a += ws[i];
    #pragma unroll
    for (int off = 32; off > 0; off >>= 1) a += __shfl_down(a, off, 64);
    if ((threadIdx.x & 63) == 0) s[threadIdx.x >> 6] = a;
    __syncthreads();
    if (threadIdx.x == 0) {
        float t = 0.0f;
        #pragma unroll
        for (int w = 0; w < 16; ++w) t += s[w];
        out[0] = 1.0f - t * inv_n;
    }
}

// Vertical-first sliding-ring SSIM.
// Lane l owns float-column Fv of the HWC image (vertical conv is
// channel-agnostic in this view; global loads are perfectly coalesced).
// Ring correctness (R5 bugfix): prologue k=0..9 updates ONLY slots s<=k
// (weight gr[k-s]); steady-state loop is re-based at kb=10 so kb%11==10,
// making completed slot == u and weight index (u+10-s)%11 — all static.
// __launch_bounds__(256,3): 55-reg ring + weights needs ~170 VGPR budget;
// a 128 cap risks R2-style scratch spill. LDS 11.6 KB; occupancy 3 blk/CU.
__global__ __launch_bounds__(256, 3) void ssim_kernel(
    const float* __restrict__ img1, const float* __restrict__ img2,
    const float* __restrict__ window, float* __restrict__ ws,
    int H, int W, int use_partials)
{
    __shared__ float vh[2][5][LPLANE];   // 11520 B
    __shared__ float wsum[4];

    const int tid  = threadIdx.x;
    const int lane = tid & 63;
    const int wid  = tid >> 6;
    const int W3   = 3 * W;

    const int Fo0 = WIDTH * blockIdx.x;       // first output float-col
    const int Fb  = Fo0 - 15;                 // vh window base float-col
    const int Fv  = Fb + tid;                 // this lane's float-col
    const int r0  = blockIdx.y * TH;          // first output row

    // g[j] = w2d[5][j] / sqrt(w2d[5][5])  (separable 1D Gaussian)
    float gr[11];
    {
        float inv = 1.0f / sqrtf(window[60]);
        #pragma unroll
        for (int t = 0; t < 11; ++t) gr[t] = window[55 + t] * inv;
    }

    const bool colok = (Fv >= 0) && (Fv < W3);

    // phase-2 per-lane constants (valid for lane < 60 of the active wave)
    const int c    = lane % 3;
    const int pg   = lane / 3;                // 0..19 (lane<60)
    const int p0   = Fo0 / 3;
    const int ofo3 = Fo0 - 3 * p0;            // Fo0 mod 3
    const int p    = p0 + 4 * pg;             // first pixel of this lane's batch
    const int bidx = 12 * pg + c - ofo3 + 4;  // LDS read base (+4 front pad)
    const int fo_end = (Fo0 + WIDTH < W3) ? (Fo0 + WIDTH) : W3;

    // vertical accumulator ring: acc[q][slot], slot = out_row mod 11
    float acc[5][11];
    #pragma unroll
    for (int q = 0; q < 5; ++q)
        #pragma unroll
        for (int s = 0; s < 11; ++s) acc[q][s] = 0.0f;

    float ssum = 0.0f;

    const float* p1 = img1 + (long)(r0 - 5) * W3 + Fv;
    const float* p2 = img2 + (long)(r0 - 5) * W3 + Fv;

    // prime prefetch for k=0 (input row r0-5)
    float xpf = 0.0f, ypf = 0.0f;
    if (colok && (r0 - 5) >= 0 && (r0 - 5) < H) { xpf = *p1; ypf = *p2; }

    // ---------- prologue: k = 0..9, windows opening ----------
    #pragma unroll
    for (int k = 0; k < 10; ++k) {
        float xc = xpf, yc = ypf;
        p1 += W3; p2 += W3;
        int rn = r0 - 4 + k;                   // next input row
        xpf = 0.0f; ypf = 0.0f;
        if (colok && rn >= 0 && rn < H) { xpf = *p1; ypf = *p2; }

        float xx = xc * xc, yy = yc * yc, xy = xc * yc;
        #pragma unroll
        for (int s = 0; s <= k; ++s) {          // ONLY open windows (bugfix)
            float g = gr[k - s];
            acc[0][s] += g * xc;
            acc[1][s] += g * yc;
            acc[2][s] += g * xx;
            acc[3][s] += g * yy;
            acc[4][s] += g * xy;
        }
    }

    // ---------- steady state: k = 10..NSTEP-1, one output row per step ----
    for (int kb = 10; kb < NSTEP; kb += 11) {   // kb in {10,21,32}; kb%11==10
        #pragma unroll
        for (int u = 0; u < 11; ++u) {
            int k = kb + u;
            if (k < NSTEP) {
                float xc = xpf, yc = ypf;
                p1 += W3; p2 += W3;
                int rn = r0 - 4 + k;
                xpf = 0.0f; ypf = 0.0f;
                if (colok && rn >= 0 && rn < H) { xpf = *p1; ypf = *p2; }

                float xx = xc * xc, yy = yc * yc, xy = xc * yc;
                #pragma unroll
                for (int s = 0; s < 11; ++s) {
                    float g = gr[(u + 10 - s) % 11];   // static
                    acc[0][s] += g * xc;
                    acc[1][s] += g * yc;
                    acc[2][s] += g * xx;
                    acc[3][s] += g * yy;
                    acc[4][s] += g * xy;
                }

                // slot u completes (output row r0 + k - 10)
                float* vb = &vh[k & 1][0][0];
                vb[0 * LPLANE + tid + 4] = acc[0][u];
                vb[1 * LPLANE + tid + 4] = acc[1][u];
                vb[2 * LPLANE + tid + 4] = acc[2][u];
                vb[3 * LPLANE + tid + 4] = acc[3][u];
                vb[4 * LPLANE + tid + 4] = acc[4][u];
                acc[0][u] = 0.0f; acc[1][u] = 0.0f; acc[2][u] = 0.0f;
                acc[3][u] = 0.0f; acc[4][u] = 0.0f;
                __syncthreads();

                // phase 2: one wave (rotating) does horizontal conv + SSIM
                if (wid == (k & 3) && lane < 60) {
                    const float* rb = vb + bidx;
                    float h0[4] = {0,0,0,0}, h1[4] = {0,0,0,0},
                          h2[4] = {0,0,0,0}, h3[4] = {0,0,0,0},
                          h4[4] = {0,0,0,0};
                    #pragma unroll
                    for (int t = 0; t < 14; ++t) {
                        float b0 = rb[0 * LPLANE + 3 * t];
                        float b1 = rb[1 * LPLANE + 3 * t];
                        float b2 = rb[2 * LPLANE + 3 * t];
                        float b3 = rb[3 * LPLANE + 3 * t];
                        float b4 = rb[4 * LPLANE + 3 * t];
                        #pragma unroll
                        for (int i = 0; i < 4; ++i) {
                            int s = t - i;
                            if (s >= 0 && s <= 10) {     // static
                                float g = gr[s];
                                h0[i] += g * b0;
                                h1[i] += g * b1;
                                h2[i] += g * b2;
                                h3[i] += g * b3;
                                h4[i] += g * b4;
                            }
                        }
                    }
                    int o = r0 + k - 10;
                    if (o < H) {
                        const float C1 = 0.0001f, C2 = 0.0009f;
                        #pragma unroll
                        for (int i = 0; i < 4; ++i) {
                            int fo = 3 * (p + i) + c;
                            if (fo >= Fo0 && fo < fo_end) {
                                float mu1 = h0[i], mu2 = h1[i];
                                float mu11 = mu1 * mu1, mu22 = mu2 * mu2;
                                float mu12 = mu1 * mu2;
                                float s11 = h2[i] - mu11;
                                float s22 = h3[i] - mu22;
                                float s12 = h4[i] - mu12;
                                float num = (2.0f * mu12 + C1) * (2.0f * s12 + C2);
                                float den = (mu11 + mu22 + C1) * (s11 + s22 + C2);
                                ssum += num * __builtin_amdgcn_rcpf(den);
                            }
                        }
                    }
                }
            }
        }
    }

    // block reduction
    #pragma unroll
    for (int off = 32; off > 0; off >>= 1)
        ssum += __shfl_down(ssum, off, 64);
    if (lane == 0) wsum[wid] = ssum;
    __syncthreads();
    if (tid == 0) {
        float total = wsum[0] + wsum[1] + wsum[2] + wsum[3];
        if (use_partials)
            ws[blockIdx.y * gridDim.x + blockIdx.x] = total;
        else
            atomicAdd(ws, total);
    }
}

extern "C" void kernel_launch(void* const* d_in, const int* in_sizes, int n_in,
                              void* d_out, int out_size, void* d_ws, size_t ws_size,
                              hipStream_t stream) {
    const float* img1   = (const float*)d_in[0];
    const float* img2   = (const float*)d_in[1];
    const float* window = (const float*)d_in[2];
    float* out = (float*)d_out;
    float* ws  = (float*)d_ws;

    long hw = (long)in_sizes[0] / 3;
    int W = (int)(sqrt((double)hw) + 0.5);
    int H = (int)(hw / W);

    float inv_n = (float)(1.0 / ((double)H * (double)W * 3.0));

    int gx = (3 * W + WIDTH - 1) / WIDTH;         // 28 for W=2048
    int gy = (H + TH - 1) / TH;                   // 64 for H=2048
    dim3 grid(gx, gy);
    long nblocks = (long)gx * gy;
    int use_partials = (ws_size >= (size_t)nblocks * sizeof(float)) ? 1 : 0;

    if (use_partials) {
        ssim_kernel<<<grid, 256, 0, stream>>>(img1, img2, window, ws, H, W, 1);
        reduce_kernel<<<1, 1024, 0, stream>>>(ws, out, (int)nblocks, inv_n);
    } else {
        zero_kernel<<<1, 1, 0, stream>>>(ws);
        ssim_kernel<<<grid, 256, 0, stream>>>(img1, img2, window, ws, H, W, 0);
        finalize_kernel<<<1, 1, 0, stream>>>(ws, out, inv_n);
    }
}